// Round 12
// baseline (35.036 us; speedup 1.0000x reference)
//
#include <hip/hip_runtime.h>
#include <math.h>

#define NC     10
#define ACP    12     // A-col stride in floats (48B, 16B aligned)
#define NM     128
#define NGEN   4
#define NPT    1023
#define NTREES 1024

// ws layout in FLOAT units:
//   ac  f32 [4][10][12]      offset 0          (480)
//   pi  f32 [4][12]          offset 480        (48)
//   bt16 packed [4][128][8]  offset 528        (4096 dword slots)
#define WS_AC(g)   ((g) * (NC * ACP))
#define WS_PI(g)   (4 * NC * ACP + (g) * ACP)
#define WS_BT(g)   (4 * NC * ACP + 4 * ACP + (g) * (NM * 8))
#define WS_FLOATS  (4 * NC * ACP + 4 * ACP + 4 * NM * 8)

#define RCPF(x) __builtin_amdgcn_rcpf(x)
#define WAVE_FENCE() __builtin_amdgcn_wave_barrier()

struct F12 { float4 a, b, c; };

__device__ __forceinline__ F12 ld12(const float* p) {
    F12 r; const float4* q = (const float4*)p;
    r.a = q[0]; r.b = q[1]; r.c = q[2]; return r;
}
__device__ __forceinline__ void unpack10(float* t, const F12& r) {
    t[0] = r.a.x; t[1] = r.a.y; t[2] = r.a.z; t[3] = r.a.w;
    t[4] = r.b.x; t[5] = r.b.y; t[6] = r.b.z; t[7] = r.b.w;
    t[8] = r.c.x; t[9] = r.c.y;
}
__device__ __forceinline__ void fma10(float* t, const F12& c, float s) {
    t[0] += c.a.x * s; t[1] += c.a.y * s; t[2] += c.a.z * s; t[3] += c.a.w * s;
    t[4] += c.b.x * s; t[5] += c.b.y * s; t[6] += c.b.z * s; t[7] += c.b.w * s;
    t[8] += c.c.x * s; t[9] += c.c.y * s;
}
__device__ __forceinline__ float sum10(const float* v) {
    return (((v[0] + v[1]) + (v[2] + v[3])) + ((v[4] + v[5]) + (v[6] + v[7]))) + (v[8] + v[9]);
}

// load one packed bf16 row (10 states) from LDS: b128 + b32, decode to f32.
__device__ __forceinline__ void ldrow10(const unsigned int* t16, int m, float* o) {
    const unsigned int* p = t16 + m * 8;
    uint4 d = *(const uint4*)p;
    unsigned int q = p[4];
    o[0] = __uint_as_float(d.x << 16); o[1] = __uint_as_float(d.x & 0xffff0000u);
    o[2] = __uint_as_float(d.y << 16); o[3] = __uint_as_float(d.y & 0xffff0000u);
    o[4] = __uint_as_float(d.z << 16); o[5] = __uint_as_float(d.z & 0xffff0000u);
    o[6] = __uint_as_float(d.w << 16); o[7] = __uint_as_float(d.w & 0xffff0000u);
    o[8] = __uint_as_float(q << 16);   o[9] = __uint_as_float(q & 0xffff0000u);
}

// ---- telescoped 3-node groups (validated exact in R11) -------------------
// {leaf0, leaf1, parent}: one log + one rcp covers all three nodes.
__device__ __forceinline__ float group3_leaf(const F12* acol, const unsigned int* bt16,
                                             const float* piv,
                                             int xl0, int xl1, int xp, float* bout) {
    float r0[NC], r1[NC], rp[NC];
    ldrow10(bt16, xl0, r0);
    ldrow10(bt16, xl1, r1);
    ldrow10(bt16, xp, rp);
    float b0[NC], b1[NC];
    #pragma unroll
    for (int j = 0; j < NC; ++j) { b0[j] = piv[j] * r0[j]; b1[j] = piv[j] * r1[j]; }
    const float nu0 = sum10(b0), nu1 = sum10(b1);
    float t[NC];
    #pragma unroll
    for (int i = 0; i < NC; ++i) t[i] = 0.f;
    #pragma unroll
    for (int j = 0; j < NC; ++j) fma10(t, acol[j], b0[j] * nu1 + b1[j] * nu0);
    #pragma unroll
    for (int i = 0; i < NC; ++i) t[i] *= rp[i];
    const float nup = sum10(t);
    const float r = RCPF(nup);
    #pragma unroll
    for (int j = 0; j < NC; ++j) bout[j] = t[j] * r;
    return __logf(nup);
}

// unnormalized node from two normalized children
__device__ __forceinline__ float node_unnorm(const F12* acol, const unsigned int* bt16,
                                             const float* c0, const float* c1,
                                             int xv, float* uo) {
    float rp[NC];
    ldrow10(bt16, xv, rp);
    float t[NC];
    #pragma unroll
    for (int i = 0; i < NC; ++i) t[i] = 0.f;
    #pragma unroll
    for (int j = 0; j < NC; ++j) fma10(t, acol[j], c0[j] + c1[j]);
    #pragma unroll
    for (int i = 0; i < NC; ++i) { t[i] *= rp[i]; uo[i] = t[i]; }
    return sum10(t);
}

// {unnorm u0, unnorm u1, parent}: one log + one rcp.
__device__ __forceinline__ float group3_mid(const F12* acol, const unsigned int* bt16,
                                            const float* u0, float nu0,
                                            const float* u1, float nu1,
                                            int xp, float* bout) {
    float rp[NC];
    ldrow10(bt16, xp, rp);
    float t[NC];
    #pragma unroll
    for (int i = 0; i < NC; ++i) t[i] = 0.f;
    #pragma unroll
    for (int j = 0; j < NC; ++j) fma10(t, acol[j], u0[j] * nu1 + u1[j] * nu0);
    #pragma unroll
    for (int i = 0; i < NC; ++i) t[i] *= rp[i];
    const float nup = sum10(t);
    const float r = RCPF(nup);
    #pragma unroll
    for (int j = 0; j < NC; ++j) bout[j] = t[j] * r;
    return __logf(nup);
}

// fused 2-level tail step, in place (stride 64), telescoped (1 log, 1 rcp).
__device__ __forceinline__ float fused_step_ip(const F12* acol, const unsigned int* bt16,
                                               float* buf, int l,
                                               int xc0, int xc1, int xp)
{
    float rc0[NC], rc1[NC], rp[NC];
    ldrow10(bt16, xc0, rc0);
    ldrow10(bt16, xc1, rc1);
    ldrow10(bt16, xp, rp);
    float t0[NC], t1[NC];
    #pragma unroll
    for (int i = 0; i < NC; ++i) { t0[i] = 0.f; t1[i] = 0.f; }
    #pragma unroll
    for (int j = 0; j < NC; ++j) {
        float4 gv = *(const float4*)(buf + j * 64 + 4 * l);
        fma10(t0, acol[j], gv.x + gv.y);
        fma10(t1, acol[j], gv.z + gv.w);
    }
    #pragma unroll
    for (int i = 0; i < NC; ++i) { t0[i] *= rc0[i]; t1[i] *= rc1[i]; }
    const float nu0 = sum10(t0), nu1 = sum10(t1);
    float tp[NC];
    #pragma unroll
    for (int i = 0; i < NC; ++i) tp[i] = 0.f;
    #pragma unroll
    for (int j = 0; j < NC; ++j) fma10(tp, acol[j], t0[j] * nu1 + t1[j] * nu0);
    #pragma unroll
    for (int i = 0; i < NC; ++i) tp[i] *= rp[i];
    const float nup = sum10(tp);
    const float rpn = RCPF(nup);
    #pragma unroll
    for (int j = 0; j < NC; ++j) buf[j * 64 + l] = tp[j] * rpn;
    return __logf(nup);
}

// ---------------- kernel 0: softmax tables into ws (runs once, 4 blocks) ----
__global__ __launch_bounds__(128)
void htmm_setup(const float* __restrict__ A,
                const float* __restrict__ B,
                const float* __restrict__ Pi,
                float* __restrict__ ws)
{
    __shared__ float sm[NC][NM];
    const int g = blockIdx.x;
    const int tid = threadIdx.x;
    const int wave = tid >> 6, lane = tid & 63;

    // B row softmax over m (no-max: |2.5 N| small, exp safe — validated R11)
    for (int c = wave; c < NC; c += 2) {
        float e0 = __expf(B[(c * NM + lane) * NGEN + g]);
        float e1 = __expf(B[(c * NM + lane + 64) * NGEN + g]);
        float s = e0 + e1;
        #pragma unroll
        for (int off = 32; off; off >>= 1) s += __shfl_xor(s, off);
        const float rs = 1.f / s;
        sm[c][lane] = e0 * rs;
        sm[c][lane + 64] = e1 * rs;
    }
    if (tid < NC) {   // A column softmax, 0.5 folded, col-major, pad 12
        const int j = tid;
        float col[NC], mx = -1e30f;
        #pragma unroll
        for (int i = 0; i < NC; ++i) { col[i] = A[(i * NC + j) * NGEN + g]; mx = fmaxf(mx, col[i]); }
        float s = 0.f;
        #pragma unroll
        for (int i = 0; i < NC; ++i) { col[i] = __expf(col[i] - mx); s += col[i]; }
        const float rs = 0.5f / s;
        float* ac = ws + WS_AC(g) + j * ACP;
        #pragma unroll
        for (int i = 0; i < NC; ++i) ac[i] = col[i] * rs;
        ac[10] = 0.f; ac[11] = 0.f;
    }
    if (tid == 16) {  // Pi softmax, pad 12
        float col[NC], mx = -1e30f;
        #pragma unroll
        for (int i = 0; i < NC; ++i) { col[i] = Pi[i * NGEN + g]; mx = fmaxf(mx, col[i]); }
        float s = 0.f;
        #pragma unroll
        for (int i = 0; i < NC; ++i) { col[i] = __expf(col[i] - mx); s += col[i]; }
        const float rs = 1.f / s;
        float* pp = ws + WS_PI(g);
        #pragma unroll
        for (int i = 0; i < NC; ++i) pp[i] = col[i] * rs;
        pp[10] = 0.f; pp[11] = 0.f;
    }
    __syncthreads();

    // pack row m: 10 states as bf16 (RNE) into 5 dwords, stride 8 dwords
    {
        const int m = tid;   // 128 threads
        unsigned int* bt = (unsigned int*)(ws + WS_BT(g)) + m * 8;
        unsigned int d[5];
        #pragma unroll
        for (int k = 0; k < 5; ++k) {
            unsigned int u0 = __float_as_uint(sm[2 * k][m]);
            unsigned int u1 = __float_as_uint(sm[2 * k + 1][m]);
            unsigned int b0 = (u0 + 0x7fffu + ((u0 >> 16) & 1u)) >> 16;
            unsigned int b1 = (u1 + 0x7fffu + ((u1 >> 16) & 1u)) >> 16;
            d[k] = b0 | (b1 << 16);
        }
        bt[0] = d[0]; bt[1] = d[1]; bt[2] = d[2]; bt[3] = d[3]; bt[4] = d[4];
        bt[5] = 0u; bt[6] = 0u; bt[7] = 0u;
    }
}

// ---------------- kernel 1: main, 4 (tree,g) units per block ----------------
// Lane = one L6 subtree sequentially in registers; A in 30 VGPRs; B-rows
// gathered from a 4KB packed-bf16 LDS table (b128+b32 per row — 2.4x fewer
// bank touches than f32). Setup softmax dedup'd to kernel 0.
// NO launch_bounds min-waves (R7: caps VGPR -> 600MB scratch spill).
__global__ __launch_bounds__(256)
void htmm_main(const int* __restrict__ x,
               const float* __restrict__ ws,
               float* __restrict__ out)
{
    __shared__ __align__(16) unsigned int sBT16[NM * 8];   // 4KB packed table
    __shared__ __align__(16) float sB6[4][NC][64];         // per-unit SoA tail buf

    const int bid = blockIdx.x;
    const int g = bid >> 8;
    const int treeBase = (bid & 255) * 4;
    const int tid = threadIdx.x;
    const int u = tid >> 6, lane = tid & 63;

    const int tree = treeBase + u;
    const int tb = tree * NPT;

    // ---- stage the packed table: 1024 dwords, 1 x uint4 per thread ----
    {
        const unsigned int* src = (const unsigned int*)(ws + WS_BT(g));
        uint4 v = *(const uint4*)(src + tid * 4);
        *(uint4*)(sBT16 + tid * 4) = v;
    }

    // ---- hoisted observation-index loads (overlap copy latency) ----
    int xl[8];
    #pragma unroll
    for (int k = 0; k < 8; ++k) xl[k] = x[tb + 511 + 8 * lane + k];
    int x8v[4];
    #pragma unroll
    for (int c = 0; c < 4; ++c) x8v[c] = x[tb + 255 + 4 * lane + c];
    const int x7a = x[tb + 127 + 2 * lane];
    const int x7b = x[tb + 128 + 2 * lane];
    const int x6v = x[tb + 63 + lane];

    // ---- A columns + pi into registers (uniform global loads, L2-hit) ----
    F12 acol[NC];
    #pragma unroll
    for (int j = 0; j < NC; ++j) acol[j] = ld12(ws + WS_AC(g) + j * ACP);
    float piv[NC];
    {
        F12 pv = ld12(ws + WS_PI(g));
        unpack10(piv, pv);
    }
    __syncthreads();

    float llacc;
    float ba[NC], bb[NC], u7a[NC], u7b[NC];

    // left half: two leaf-groups -> unnormalized L7a
    llacc  = group3_leaf(acol, sBT16, piv, xl[0], xl[1], x8v[0], ba);
    llacc += group3_leaf(acol, sBT16, piv, xl[2], xl[3], x8v[1], bb);
    const float nu7a = node_unnorm(acol, sBT16, ba, bb, x7a, u7a);

    // right half
    llacc += group3_leaf(acol, sBT16, piv, xl[4], xl[5], x8v[2], ba);
    llacc += group3_leaf(acol, sBT16, piv, xl[6], xl[7], x8v[3], bb);
    const float nu7b = node_unnorm(acol, sBT16, ba, bb, x7b, u7b);

    // {L7a, L7b, L6} telescoped -> normalized L6 beta
    llacc += group3_mid(acol, sBT16, u7a, nu7a, u7b, nu7b, x6v, ba);
    #pragma unroll
    for (int j = 0; j < NC; ++j) sB6[u][j][lane] = ba[j];

    // ---- tail: levels 5..0, wave-local, in place in sB6 ----
    WAVE_FENCE();
    float lla = 0.f;
    if (lane < 16)
        lla = fused_step_ip(acol, sBT16, &sB6[u][0][0], lane,
                            x[tb + 31 + 2 * lane], x[tb + 32 + 2 * lane],
                            x[tb + 15 + lane]);
    llacc += lla;
    WAVE_FENCE();
    float llb = 0.f;
    if (lane < 4)
        llb = fused_step_ip(acol, sBT16, &sB6[u][0][0], lane,
                            x[tb + 7 + 2 * lane], x[tb + 8 + 2 * lane],
                            x[tb + 3 + lane]);
    llacc += llb;
    WAVE_FENCE();
    if (lane == 0)
        llacc += fused_step_ip(acol, sBT16, &sB6[u][0][0], 0,
                               x[tb + 1], x[tb + 2], x[tb + 0]);

    // ---- full-wave reduce; lane 0 writes the unit's output ----
    #pragma unroll
    for (int off = 32; off; off >>= 1) llacc += __shfl_down(llacc, off);
    if (lane == 0) out[tree * NGEN + g] = llacc;
}

// ---------------- fallback: R11 monolithic (known-good, 26.1 µs) ------------
__device__ __forceinline__ void mul10f(float* t, const F12& r) {
    t[0] *= r.a.x; t[1] *= r.a.y; t[2] *= r.a.z; t[3] *= r.a.w;
    t[4] *= r.b.x; t[5] *= r.b.y; t[6] *= r.b.z; t[7] *= r.b.w;
    t[8] *= r.c.x; t[9] *= r.c.y;
}
#define NCP 12
__global__ __launch_bounds__(256)
void htmm_fused(const int* __restrict__ x,
                const float* __restrict__ A,
                const float* __restrict__ B,
                const float* __restrict__ Pi,
                float* __restrict__ out)
{
    __shared__ __align__(16) float sACol[NC][NCP];
    __shared__ __align__(16) float sBT[NM][NCP];
    __shared__ __align__(16) float sBTpi[NM][NCP];
    __shared__ __align__(16) float sPiP[NCP];
    __shared__ __align__(16) float sB6[4][NC][64];

    const int bid = blockIdx.x;
    const int g = bid >> 8;
    const int treeBase = (bid & 255) * 4;
    const int tid = threadIdx.x;
    const int u = tid >> 6, lane = tid & 63;
    const int tree = treeBase + u;
    const int tb = tree * NPT;

    int xl[8];
    #pragma unroll
    for (int k = 0; k < 8; ++k) xl[k] = x[tb + 511 + 8 * lane + k];
    int x8v[4];
    #pragma unroll
    for (int c = 0; c < 4; ++c) x8v[c] = x[tb + 255 + 4 * lane + c];
    const int x7a = x[tb + 127 + 2 * lane];
    const int x7b = x[tb + 128 + 2 * lane];
    const int x6v = x[tb + 63 + lane];

    for (int c = u; c < NC; c += 4) {
        float e0 = __expf(B[(c * NM + lane) * NGEN + g]);
        float e1 = __expf(B[(c * NM + lane + 64) * NGEN + g]);
        float sm = e0 + e1;
        #pragma unroll
        for (int off = 32; off; off >>= 1) sm += __shfl_xor(sm, off);
        const float rs = 1.f / sm;
        sBT[lane][c]      = e0 * rs;
        sBT[lane + 64][c] = e1 * rs;
    }
    if (tid >= 128 && tid < 128 + NC) {
        const int j = tid - 128;
        float col[NC], mx = -1e30f;
        #pragma unroll
        for (int i = 0; i < NC; ++i) { col[i] = A[(i * NC + j) * NGEN + g]; mx = fmaxf(mx, col[i]); }
        float sm = 0.f;
        #pragma unroll
        for (int i = 0; i < NC; ++i) { col[i] = __expf(col[i] - mx); sm += col[i]; }
        const float rs = 0.5f / sm;
        #pragma unroll
        for (int i = 0; i < NC; ++i) sACol[j][i] = col[i] * rs;
    }
    if (tid == 192) {
        float col[NC], mx = -1e30f;
        #pragma unroll
        for (int i = 0; i < NC; ++i) { col[i] = Pi[i * NGEN + g]; mx = fmaxf(mx, col[i]); }
        float sm = 0.f;
        #pragma unroll
        for (int i = 0; i < NC; ++i) { col[i] = __expf(col[i] - mx); sm += col[i]; }
        const float rs = 1.f / sm;
        #pragma unroll
        for (int i = 0; i < NC; ++i) sPiP[i] = col[i] * rs;
    }
    __syncthreads();
    if (tid < NM) {
        F12 pi = ld12(sPiP);
        F12 r  = ld12(&sBT[tid][0]);
        sBTpi[tid][0] = pi.a.x * r.a.x; sBTpi[tid][1] = pi.a.y * r.a.y;
        sBTpi[tid][2] = pi.a.z * r.a.z; sBTpi[tid][3] = pi.a.w * r.a.w;
        sBTpi[tid][4] = pi.b.x * r.b.x; sBTpi[tid][5] = pi.b.y * r.b.y;
        sBTpi[tid][6] = pi.b.z * r.b.z; sBTpi[tid][7] = pi.b.w * r.b.w;
        sBTpi[tid][8] = pi.c.x * r.c.x; sBTpi[tid][9] = pi.c.y * r.c.y;
    }
    __syncthreads();

    F12 acol[NC];
    #pragma unroll
    for (int j = 0; j < NC; ++j) acol[j] = ld12(&sACol[j][0]);

    float llacc;
    float ba[NC], bb[NC], u7a[NC], u7b[NC];

    // group3_leaf inline (f32 tables)
    {
        float b0[NC], b1[NC], t[NC];
        // 1
        unpack10(b0, ld12(&sBTpi[xl[0]][0])); unpack10(b1, ld12(&sBTpi[xl[1]][0]));
        float nu0 = sum10(b0), nu1 = sum10(b1);
        #pragma unroll
        for (int i = 0; i < NC; ++i) t[i] = 0.f;
        #pragma unroll
        for (int j = 0; j < NC; ++j) fma10(t, acol[j], b0[j] * nu1 + b1[j] * nu0);
        mul10f(t, ld12(&sBT[x8v[0]][0]));
        float nup = sum10(t); float r = RCPF(nup);
        #pragma unroll
        for (int j = 0; j < NC; ++j) ba[j] = t[j] * r;
        llacc = __logf(nup);
        // 2
        unpack10(b0, ld12(&sBTpi[xl[2]][0])); unpack10(b1, ld12(&sBTpi[xl[3]][0]));
        nu0 = sum10(b0); nu1 = sum10(b1);
        #pragma unroll
        for (int i = 0; i < NC; ++i) t[i] = 0.f;
        #pragma unroll
        for (int j = 0; j < NC; ++j) fma10(t, acol[j], b0[j] * nu1 + b1[j] * nu0);
        mul10f(t, ld12(&sBT[x8v[1]][0]));
        nup = sum10(t); r = RCPF(nup);
        #pragma unroll
        for (int j = 0; j < NC; ++j) bb[j] = t[j] * r;
        llacc += __logf(nup);
        // L7a unnorm
        #pragma unroll
        for (int i = 0; i < NC; ++i) t[i] = 0.f;
        #pragma unroll
        for (int j = 0; j < NC; ++j) fma10(t, acol[j], ba[j] + bb[j]);
        mul10f(t, ld12(&sBT[x7a][0]));
        #pragma unroll
        for (int i = 0; i < NC; ++i) u7a[i] = t[i];
        const float nu7a = sum10(t);
        // 3
        unpack10(b0, ld12(&sBTpi[xl[4]][0])); unpack10(b1, ld12(&sBTpi[xl[5]][0]));
        nu0 = sum10(b0); nu1 = sum10(b1);
        #pragma unroll
        for (int i = 0; i < NC; ++i) t[i] = 0.f;
        #pragma unroll
        for (int j = 0; j < NC; ++j) fma10(t, acol[j], b0[j] * nu1 + b1[j] * nu0);
        mul10f(t, ld12(&sBT[x8v[2]][0]));
        nup = sum10(t); r = RCPF(nup);
        #pragma unroll
        for (int j = 0; j < NC; ++j) ba[j] = t[j] * r;
        llacc += __logf(nup);
        // 4
        unpack10(b0, ld12(&sBTpi[xl[6]][0])); unpack10(b1, ld12(&sBTpi[xl[7]][0]));
        nu0 = sum10(b0); nu1 = sum10(b1);
        #pragma unroll
        for (int i = 0; i < NC; ++i) t[i] = 0.f;
        #pragma unroll
        for (int j = 0; j < NC; ++j) fma10(t, acol[j], b0[j] * nu1 + b1[j] * nu0);
        mul10f(t, ld12(&sBT[x8v[3]][0]));
        nup = sum10(t); r = RCPF(nup);
        #pragma unroll
        for (int j = 0; j < NC; ++j) bb[j] = t[j] * r;
        llacc += __logf(nup);
        // L7b unnorm
        #pragma unroll
        for (int i = 0; i < NC; ++i) t[i] = 0.f;
        #pragma unroll
        for (int j = 0; j < NC; ++j) fma10(t, acol[j], ba[j] + bb[j]);
        mul10f(t, ld12(&sBT[x7b][0]));
        #pragma unroll
        for (int i = 0; i < NC; ++i) u7b[i] = t[i];
        const float nu7b = sum10(t);
        // L6 group
        #pragma unroll
        for (int i = 0; i < NC; ++i) t[i] = 0.f;
        #pragma unroll
        for (int j = 0; j < NC; ++j) fma10(t, acol[j], u7a[j] * nu7b + u7b[j] * nu7a);
        mul10f(t, ld12(&sBT[x6v][0]));
        nup = sum10(t); r = RCPF(nup);
        #pragma unroll
        for (int j = 0; j < NC; ++j) sB6[u][j][lane] = t[j] * r;
        llacc += __logf(nup);
    }

    WAVE_FENCE();
    // f32 tail
    {
        float lla = 0.f;
        if (lane < 16) {
            float t0[NC], t1[NC], tp[NC];
            #pragma unroll
            for (int i = 0; i < NC; ++i) { t0[i] = 0.f; t1[i] = 0.f; }
            float* buf = &sB6[u][0][0];
            #pragma unroll
            for (int j = 0; j < NC; ++j) {
                float4 gv = *(const float4*)(buf + j * 64 + 4 * lane);
                fma10(t0, acol[j], gv.x + gv.y);
                fma10(t1, acol[j], gv.z + gv.w);
            }
            mul10f(t0, ld12(&sBT[x[tb + 31 + 2 * lane]][0]));
            mul10f(t1, ld12(&sBT[x[tb + 32 + 2 * lane]][0]));
            const float nu0 = sum10(t0), nu1 = sum10(t1);
            #pragma unroll
            for (int i = 0; i < NC; ++i) tp[i] = 0.f;
            #pragma unroll
            for (int j = 0; j < NC; ++j) fma10(tp, acol[j], t0[j] * nu1 + t1[j] * nu0);
            mul10f(tp, ld12(&sBT[x[tb + 15 + lane]][0]));
            const float nup = sum10(tp); const float rp = RCPF(nup);
            #pragma unroll
            for (int j = 0; j < NC; ++j) buf[j * 64 + lane] = tp[j] * rp;
            lla = __logf(nup);
        }
        llacc += lla;
        WAVE_FENCE();
        float llb = 0.f;
        if (lane < 4) {
            float t0[NC], t1[NC], tp[NC];
            #pragma unroll
            for (int i = 0; i < NC; ++i) { t0[i] = 0.f; t1[i] = 0.f; }
            float* buf = &sB6[u][0][0];
            #pragma unroll
            for (int j = 0; j < NC; ++j) {
                float4 gv = *(const float4*)(buf + j * 64 + 4 * lane);
                fma10(t0, acol[j], gv.x + gv.y);
                fma10(t1, acol[j], gv.z + gv.w);
            }
            mul10f(t0, ld12(&sBT[x[tb + 7 + 2 * lane]][0]));
            mul10f(t1, ld12(&sBT[x[tb + 8 + 2 * lane]][0]));
            const float nu0 = sum10(t0), nu1 = sum10(t1);
            #pragma unroll
            for (int i = 0; i < NC; ++i) tp[i] = 0.f;
            #pragma unroll
            for (int j = 0; j < NC; ++j) fma10(tp, acol[j], t0[j] * nu1 + t1[j] * nu0);
            mul10f(tp, ld12(&sBT[x[tb + 3 + lane]][0]));
            const float nup = sum10(tp); const float rp = RCPF(nup);
            #pragma unroll
            for (int j = 0; j < NC; ++j) buf[j * 64 + lane] = tp[j] * rp;
            llb = __logf(nup);
        }
        llacc += llb;
        WAVE_FENCE();
        if (lane == 0) {
            float t0[NC], t1[NC], tp[NC];
            #pragma unroll
            for (int i = 0; i < NC; ++i) { t0[i] = 0.f; t1[i] = 0.f; }
            float* buf = &sB6[u][0][0];
            #pragma unroll
            for (int j = 0; j < NC; ++j) {
                float4 gv = *(const float4*)(buf + j * 64);
                fma10(t0, acol[j], gv.x + gv.y);
                fma10(t1, acol[j], gv.z + gv.w);
            }
            mul10f(t0, ld12(&sBT[x[tb + 1]][0]));
            mul10f(t1, ld12(&sBT[x[tb + 2]][0]));
            const float nu0 = sum10(t0), nu1 = sum10(t1);
            #pragma unroll
            for (int i = 0; i < NC; ++i) tp[i] = 0.f;
            #pragma unroll
            for (int j = 0; j < NC; ++j) fma10(tp, acol[j], t0[j] * nu1 + t1[j] * nu0);
            mul10f(tp, ld12(&sBT[x[tb]][0]));
            llacc += __logf(sum10(tp));
        }
    }

    #pragma unroll
    for (int off = 32; off; off >>= 1) llacc += __shfl_down(llacc, off);
    if (lane == 0) out[tree * NGEN + g] = llacc;
}

extern "C" void kernel_launch(void* const* d_in, const int* in_sizes, int n_in,
                              void* d_out, int out_size, void* d_ws, size_t ws_size,
                              hipStream_t stream) {
    const int*   x  = (const int*)d_in[0];
    const float* A  = (const float*)d_in[1];
    const float* B  = (const float*)d_in[2];
    const float* Pi = (const float*)d_in[3];
    float* out = (float*)d_out;

    if (ws_size >= (size_t)WS_FLOATS * sizeof(float)) {
        float* ws = (float*)d_ws;
        htmm_setup<<<NGEN, 128, 0, stream>>>(A, B, Pi, ws);
        htmm_main<<<NTREES, 256, 0, stream>>>(x, ws, out);
    } else {
        htmm_fused<<<NTREES, 256, 0, stream>>>(x, A, B, Pi, out);
    }
}